// Round 1
// baseline (1459.263 us; speedup 1.0000x reference)
//
#include <hip/hip_runtime.h>
#include <hip/hip_bf16.h>

// GroupedExperts: out = (silu(x@gate) * (x@down)) @ up  per expert.
// E=8, T=4096, D_IN=2048, D_H=1408. fp32 in/out, bf16 MFMA internally.
//
// This version replaces the 128x128/BK32 2-barrier GEMM (m97-structure,
// ~768/384 TF) with a 256-wide-tile, BK=64, 8-wave, double-buffered,
// 4-phase-per-K-tile schedule (T2 swizzle + T3-lite phase interleave +
// T5 setprio + T1 XCD swizzle). Prefetch for tile k+1 is issued at the
// START of tile k; a single vmcnt(0) drain per K-tile lands ~3 MFMA
// phases after issue.

typedef __bf16 bf16x8 __attribute__((ext_vector_type(8)));
typedef float  f32x4  __attribute__((ext_vector_type(4)));

__device__ __forceinline__ void gload16(const void* g, void* l) {
  // async global->LDS, 16B per lane; LDS dest = wave-uniform base + lane*16
  __builtin_amdgcn_global_load_lds((const __attribute__((address_space(1))) void*)g,
                                   (__attribute__((address_space(3))) void*)l,
                                   16, 0, 0);
}

__device__ __forceinline__ unsigned short f2bf(float f) {
  union { float fv; unsigned u; } v; v.fv = f;
  unsigned r = (v.u + 0x7fffu + ((v.u >> 16) & 1u)) >> 16;  // RNE
  return (unsigned short)r;
}

// ------------- cast fp32 -> bf16, flat, vectorized -------------------------
__global__ __launch_bounds__(256)
void cvt_f32_bf16(const float* __restrict__ in, unsigned short* __restrict__ out,
                  long n) {
  long i = ((long)blockIdx.x * 256 + threadIdx.x) * 4;
  const long stride = (long)gridDim.x * 1024;
  for (; i < n; i += stride) {
    const float4 v = *(const float4*)(in + i);
    ushort4 o;
    o.x = f2bf(v.x); o.y = f2bf(v.y); o.z = f2bf(v.z); o.w = f2bf(v.w);
    *(ushort4*)(out + i) = o;
  }
}

// ------------- transpose+cast: fp32 [E][R][C] -> bf16 [E][C][R] ------------
__global__ __launch_bounds__(256)
void trcvt(const float* __restrict__ in, unsigned short* __restrict__ out,
           int R, int C) {
  __shared__ unsigned short tile[32][33];
  const float* src = in + (size_t)blockIdx.z * R * C;
  unsigned short* dst = out + (size_t)blockIdx.z * R * C;
  const int c0 = blockIdx.x << 5, r0 = blockIdx.y << 5;
  const int tx = threadIdx.x, ty = threadIdx.y;  // block (32,8)
#pragma unroll
  for (int i = 0; i < 32; i += 8)
    tile[ty + i][tx] = f2bf(src[(size_t)(r0 + ty + i) * C + (c0 + tx)]);
  __syncthreads();
#pragma unroll
  for (int i = 0; i < 32; i += 8)
    dst[(size_t)(c0 + ty + i) * R + (r0 + tx)] = tile[tx][ty + i];
}

// --------------- phase-split GEMM: C[4096][NDIM] = A[4096][KDIM] @ B^T -----
// A, B0, B1 bf16 row-major [rows][KDIM] (B pre-transposed).
// FUSED: C = silu(A@B0)*(A@B1), bf16 out, BM=256 BN=128.
// else:  C = A@B0, fp32 out (F32OUT),   BM=256 BN=256.
// 512 threads = 8 waves. BK=64. Double-buffered LDS (128 KiB total).
// LDS swizzle: 16B-chunk index c stored at c ^ (row&7)  (conflict-free
// ds_read_b128; global_load_lds lane sources pre-permuted to match).
// Per K-tile: 4 phases, each {ds_read frags; s_barrier; lgkmcnt(0);
// setprio(1); 16 MFMA; setprio(0); s_barrier}. All 8 prefetch loads for
// tile k+1 issued before phase 0 of tile k; vmcnt(0) only at tile end.
template <int KDIM, int NDIM, bool FUSED, bool F32OUT>
__global__ __launch_bounds__(512, 2)
void gemm8p(const unsigned short* __restrict__ A,
            const unsigned short* __restrict__ B0,
            const unsigned short* __restrict__ B1,
            void* __restrict__ Cout) {
  constexpr int BM  = 256;
  constexpr int BN  = FUSED ? 128 : 256;
  constexpr int NB_N = NDIM / BN;
  constexpr int NKT = KDIM / 64;
  constexpr int PMI = FUSED ? 2 : 4;   // M-frags per phase
  constexpr int NMI = FUSED ? 4 : 8;   // M-frags per wave

  __shared__ __align__(16) unsigned short sA[2][BM * 64];
  __shared__ __align__(16) unsigned short sB[2][(FUSED ? 2 : 1) * BN * 64];

  const int t = threadIdx.x;
  const int w = t >> 6;
  const int lane = t & 63;
  const int e = blockIdx.y;

  // bijective XCD swizzle within expert (gridDim.x % 8 == 0 for both GEMMs)
  const int cpx = gridDim.x >> 3;
  const int bid = (blockIdx.x & 7) * cpx + (blockIdx.x >> 3);
  const int m0 = (bid / NB_N) << 8;
  const int n0 = (bid % NB_N) * BN;

  const unsigned short* Ae  = A  + (size_t)e * 4096 * KDIM;
  const unsigned short* B0e = B0 + (size_t)e * NDIM * KDIM;

  // staging: segment = 8 rows x 64 elems = 1024B; wave-uniform LDS base
  // = seg*1024; lane l writes row (l>>3), chunk-slot (l&7). To realize the
  // swizzle (stored slot s holds logical chunk s ^ (row&7)), lane l fetches
  // global chunk (l&7) ^ (l>>3) of row (l>>3).
  const int l8 = lane >> 3;
  const int lc = ((lane & 7) ^ l8) << 3;   // element offset of fetched chunk

  const unsigned short* aSrc[4];
  const unsigned short* bSrc[4];   // FUSED: [0..1]=B0 segs, [2..3]=B1 segs
#pragma unroll
  for (int i = 0; i < 4; ++i)
    aSrc[i] = Ae + (size_t)(m0 + ((4 * w + i) << 3) + l8) * KDIM + lc;
  if constexpr (FUSED) {
    const unsigned short* B1e = B1 + (size_t)e * NDIM * KDIM;
#pragma unroll
    for (int j = 0; j < 2; ++j) {
      bSrc[j]     = B0e + (size_t)(n0 + ((2 * w + j) << 3) + l8) * KDIM + lc;
      bSrc[2 + j] = B1e + (size_t)(n0 + ((2 * w + j) << 3) + l8) * KDIM + lc;
    }
  } else {
#pragma unroll
    for (int i = 0; i < 4; ++i)
      bSrc[i] = B0e + (size_t)(n0 + ((4 * w + i) << 3) + l8) * KDIM + lc;
  }

  auto stage = [&](int nb) {
#pragma unroll
    for (int i = 0; i < 4; ++i) {
      gload16(aSrc[i], &sA[nb][(4 * w + i) << 9]);
      aSrc[i] += 64;
    }
    if constexpr (FUSED) {
#pragma unroll
      for (int j = 0; j < 2; ++j) {
        gload16(bSrc[j], &sB[nb][(2 * w + j) << 9]);
        bSrc[j] += 64;
        gload16(bSrc[2 + j], &sB[nb][(BN * 64) + ((2 * w + j) << 9)]);
        bSrc[2 + j] += 64;
      }
    } else {
#pragma unroll
      for (int i = 0; i < 4; ++i) {
        gload16(bSrc[i], &sB[nb][(4 * w + i) << 9]);
        bSrc[i] += 64;
      }
    }
  };

  // wave -> output sub-tile
  const int wm = FUSED ? ((w >> 1) << 6) : ((w >> 2) << 7);
  const int wn = FUSED ? ((w & 1) << 6) : ((w & 3) << 6);
  const int lm = lane & 15;
  const int kq = lane >> 4;

  f32x4 acc0[NMI][4];
  f32x4 acc1[FUSED ? 4 : 1][4];
  const f32x4 z = {0.f, 0.f, 0.f, 0.f};
#pragma unroll
  for (int mi = 0; mi < NMI; ++mi)
#pragma unroll
    for (int ni = 0; ni < 4; ++ni) acc0[mi][ni] = z;
  if constexpr (FUSED) {
#pragma unroll
    for (int mi = 0; mi < 4; ++mi)
#pragma unroll
      for (int ni = 0; ni < 4; ++ni) acc1[mi][ni] = z;
  }

  bf16x8 af[PMI][2], bf0[2][2], bf1[2][2];

  // fragment read: logical chunk (ks*4+kq) of row (rowbase+lm); rowbase%16==0
  // so row&7 == lm&7; stored slot = chunk ^ (lm&7).
  auto ldf = [&](const unsigned short* base, int rowbase, int ks) -> bf16x8 {
    const int r = rowbase + lm;
    const int c = ((ks << 2) + kq) ^ (lm & 7);
    return ((const bf16x8*)base)[(r << 3) + c];
  };

#define PHASE(bufA, bufB, ABLK, BPAIR, READA, TILEEND)                         \
  {                                                                            \
    if constexpr (READA) {                                                     \
      _Pragma("unroll") for (int mi = 0; mi < PMI; ++mi)                       \
        _Pragma("unroll") for (int ks = 0; ks < 2; ++ks)                       \
          af[mi][ks] = ldf(bufA, wm + (((ABLK)*PMI + mi) << 4), ks);           \
    }                                                                          \
    _Pragma("unroll") for (int nj = 0; nj < 2; ++nj)                           \
      _Pragma("unroll") for (int ks = 0; ks < 2; ++ks) {                       \
        bf0[nj][ks] = ldf(bufB, wn + (((BPAIR)*2 + nj) << 4), ks);             \
        if constexpr (FUSED)                                                   \
          bf1[nj][ks] = ldf((bufB) + BN * 64, wn + (((BPAIR)*2 + nj) << 4), ks); \
      }                                                                        \
    __builtin_amdgcn_s_barrier();                                              \
    asm volatile("s_waitcnt lgkmcnt(0)" ::: "memory");                         \
    __builtin_amdgcn_s_setprio(1);                                             \
    _Pragma("unroll") for (int mi = 0; mi < PMI; ++mi)                         \
      _Pragma("unroll") for (int nj = 0; nj < 2; ++nj)                         \
        _Pragma("unroll") for (int ks = 0; ks < 2; ++ks) {                     \
          acc0[(ABLK)*PMI + mi][(BPAIR)*2 + nj] =                              \
              __builtin_amdgcn_mfma_f32_16x16x32_bf16(                         \
                  af[mi][ks], bf0[nj][ks],                                     \
                  acc0[(ABLK)*PMI + mi][(BPAIR)*2 + nj], 0, 0, 0);             \
          if constexpr (FUSED)                                                 \
            acc1[(ABLK)*PMI + mi][(BPAIR)*2 + nj] =                            \
                __builtin_amdgcn_mfma_f32_16x16x32_bf16(                       \
                    af[mi][ks], bf1[nj][ks],                                   \
                    acc1[(ABLK)*PMI + mi][(BPAIR)*2 + nj], 0, 0, 0);           \
        }                                                                      \
    __builtin_amdgcn_s_setprio(0);                                             \
    if constexpr (TILEEND) asm volatile("s_waitcnt vmcnt(0)" ::: "memory");    \
    __builtin_amdgcn_s_barrier();                                              \
  }

  // prologue: stage tile 0, drain, sync.
  stage(0);
  asm volatile("s_waitcnt vmcnt(0)" ::: "memory");
  __builtin_amdgcn_s_barrier();

  for (int kt = 0; kt < NKT; ++kt) {
    const int cur = kt & 1;
    const unsigned short* bufA = sA[cur];
    const unsigned short* bufB = sB[cur];
    if (kt + 1 < NKT) stage(cur ^ 1);   // issue-early: drains 3 phases later
    PHASE(bufA, bufB, 0, 0, true,  false)
    PHASE(bufA, bufB, 0, 1, false, false)
    PHASE(bufA, bufB, 1, 0, true,  false)
    PHASE(bufA, bufB, 1, 1, false, true)
  }
#undef PHASE

  // epilogue: C/D layout col=lane&15, row=(lane>>4)*4+reg (m89-verified)
  const size_t cbase = (size_t)e * 4096 * NDIM;
  if constexpr (F32OUT) {
    float* C = (float*)Cout + cbase;
#pragma unroll
    for (int mi = 0; mi < NMI; ++mi)
#pragma unroll
      for (int ni = 0; ni < 4; ++ni)
#pragma unroll
        for (int i = 0; i < 4; ++i) {
          const int row = m0 + wm + (mi << 4) + (kq << 2) + i;
          const int col = n0 + wn + (ni << 4) + lm;
          C[(size_t)row * NDIM + col] = acc0[mi][ni][i];
        }
  } else {
    unsigned short* C = (unsigned short*)Cout + cbase;
#pragma unroll
    for (int mi = 0; mi < NMI; ++mi)
#pragma unroll
      for (int ni = 0; ni < 4; ++ni)
#pragma unroll
        for (int i = 0; i < 4; ++i) {
          const int row = m0 + wm + (mi << 4) + (kq << 2) + i;
          const int col = n0 + wn + (ni << 4) + lm;
          const float g = acc0[mi][ni][i];
          const float d = acc1[mi][ni][i];
          C[(size_t)row * NDIM + col] = f2bf(g / (1.0f + __expf(-g)) * d);
        }
  }
}

extern "C" void kernel_launch(void* const* d_in, const int* in_sizes, int n_in,
                              void* d_out, int out_size, void* d_ws, size_t ws_size,
                              hipStream_t stream) {
  const float* x    = (const float*)d_in[0];  // [8][4096][2048] fp32
  const float* gate = (const float*)d_in[1];  // [8][2048][1408] fp32
  const float* down = (const float*)d_in[2];  // [8][2048][1408] fp32
  const float* up   = (const float*)d_in[3];  // [8][1408][2048] fp32

  // d_out doubles as scratch for x_bf16 (134 MB < 268 MB out buffer);
  // GEMM2 overwrites it with the final fp32 result (stream-ordered, and
  // GEMM2 never reads d_out).
  unsigned short* xb = (unsigned short*)d_out;

  char* ws = (char*)d_ws;
  unsigned short* h    = (unsigned short*)ws;                   // 92,274,688 B
  unsigned short* bufG = (unsigned short*)(ws + 92274688ull);   // 46,137,344 B (gate^T, then up^T)
  unsigned short* bufD = (unsigned short*)(ws + 138412032ull);  // 46,137,344 B (down^T)
  // total ws need: 184,549,376 B

  const long nx = 8L * 4096 * 2048;
  cvt_f32_bf16<<<8192, 256, 0, stream>>>(x, xb, nx);

  dim3 tb(32, 8, 1);
  // gate/down: fp32 [2048][1408] -> bf16 [1408][2048]
  trcvt<<<dim3(44, 64, 8), tb, 0, stream>>>(gate, bufG, 2048, 1408);
  trcvt<<<dim3(44, 64, 8), tb, 0, stream>>>(down, bufD, 2048, 1408);

  // h = silu(x@gate) * (x@down):  M=4096, N=1408, K=2048, bf16 out
  // grid: 16 M-blocks x 11 N-blocks = 176 per expert (%8==0), experts in y
  gemm8p<2048, 1408, true, false><<<dim3(176, 8), 512, 0, stream>>>(xb, bufG, bufD, h);

  // up: fp32 [1408][2048] -> bf16 [2048][1408]  (reuses bufG)
  trcvt<<<dim3(64, 44, 8), tb, 0, stream>>>(up, bufG, 1408, 2048);

  // out = h @ up:  M=4096, N=2048, K=1408, fp32 out
  // grid: 16 M-blocks x 8 N-blocks = 128 per expert (%8==0)
  gemm8p<1408, 2048, false, true><<<dim3(128, 8), 512, 0, stream>>>(h, bufG, nullptr, (float*)d_out);
}

// Round 3
// 1184.309 us; speedup vs baseline: 1.2322x; 1.2322x over previous
//
#include <hip/hip_runtime.h>
#include <hip/hip_bf16.h>

// GroupedExperts: out = (silu(x@gate) * (x@down)) @ up  per expert.
// E=8, T=4096, D_IN=2048, D_H=1408. fp32 in/out, bf16 MFMA internally.
//
// Ring-pipelined GEMM (m201-style T3+T4+T5): BK=32 sub-tiles, ring-4 LDS
// (128 KiB), staging 3 sub-tiles ahead, counted s_waitcnt vmcnt(8) once per
// K-step (never 0 in steady state), 2 phases x 16 MFMA per K-step with
// setprio(1) around the MFMA cluster, XCD-swizzled grid.
// LDS: 1KB panels (16 rows x 32 k) with the m97-verified k-chunk XOR swizzle
// (slot = chunk ^ ((row>>1)&3)) -> conflict-free ds_read_b128; the
// global_load_lds per-lane SOURCE is pre-permuted to match (LDS dest linear).

typedef __bf16 bf16x8 __attribute__((ext_vector_type(8)));
typedef float  f32x4  __attribute__((ext_vector_type(4)));

__device__ __forceinline__ void gload16(const void* g, void* l) {
  // async global->LDS, 16B per lane; LDS dest = wave-uniform base + lane*16
  __builtin_amdgcn_global_load_lds((const __attribute__((address_space(1))) void*)g,
                                   (__attribute__((address_space(3))) void*)l,
                                   16, 0, 0);
}

__device__ __forceinline__ unsigned short f2bf(float f) {
  union { float fv; unsigned u; } v; v.fv = f;
  unsigned r = (v.u + 0x7fffu + ((v.u >> 16) & 1u)) >> 16;  // RNE
  return (unsigned short)r;
}

// ------------- cast fp32 -> bf16, flat, vectorized -------------------------
__global__ __launch_bounds__(256)
void cvt_f32_bf16(const float* __restrict__ in, unsigned short* __restrict__ out,
                  long n) {
  long i = ((long)blockIdx.x * 256 + threadIdx.x) * 4;
  const long stride = (long)gridDim.x * 1024;
  for (; i < n; i += stride) {
    const float4 v = *(const float4*)(in + i);
    ushort4 o;
    o.x = f2bf(v.x); o.y = f2bf(v.y); o.z = f2bf(v.z); o.w = f2bf(v.w);
    *(ushort4*)(out + i) = o;
  }
}

// ------------- transpose+cast: fp32 [E][R][C] -> bf16 [E][C][R] ------------
__global__ __launch_bounds__(256)
void trcvt(const float* __restrict__ in, unsigned short* __restrict__ out,
           int R, int C) {
  __shared__ unsigned short tile[32][33];
  const float* src = in + (size_t)blockIdx.z * R * C;
  unsigned short* dst = out + (size_t)blockIdx.z * R * C;
  const int c0 = blockIdx.x << 5, r0 = blockIdx.y << 5;
  const int tx = threadIdx.x, ty = threadIdx.y;  // block (32,8)
#pragma unroll
  for (int i = 0; i < 32; i += 8)
    tile[ty + i][tx] = f2bf(src[(size_t)(r0 + ty + i) * C + (c0 + tx)]);
  __syncthreads();
#pragma unroll
  for (int i = 0; i < 32; i += 8)
    dst[(size_t)(c0 + ty + i) * R + (r0 + tx)] = tile[tx][ty + i];
}

// --------------- ring-pipelined GEMM: C[4096][NDIM] = A[4096][KDIM] @ B^T --
// A, B0, B1 bf16 row-major [rows][KDIM] (B pre-transposed).
// FUSED: C = silu(A@B0)*(A@B1), bf16 out, BM=256 BN=128 (two B mats).
// else:  C = A@B0, fp32 out,            BM=256 BN=256.
// 512 threads = 8 waves, 1 block/CU (128 KiB LDS).
//
// Schedule per K-step s:
//   phase A: ds_read af[0..3]+bf0[0..3]; issue 2 gloads (subtile s+3);
//            s_barrier; setprio(1); 16 MFMA; setprio(0); s_barrier
//   phase B: ds_read (FUSED: bf1[0..3] / else af[4..7]); issue 2 gloads;
//            s_barrier; setprio(1); 16 MFMA; setprio(0);
//            s_waitcnt vmcnt(8)  <- waits only subtile s+1's loads; s_barrier
// Prologue stages subtiles 0..2 (12 loads), vmcnt(8), barrier.
template <int KDIM, int NDIM, bool FUSED, bool F32OUT>
__global__ __launch_bounds__(512, 2)
void gemm_ring(const unsigned short* __restrict__ A,
               const unsigned short* __restrict__ B0,
               const unsigned short* __restrict__ B1,
               void* __restrict__ Cout) {
  constexpr int BN   = FUSED ? 128 : 256;
  constexpr int NB_N = NDIM / BN;
  constexpr int NS   = KDIM / 32;     // K-steps
  constexpr int SLOT = 16384;         // ushorts per ring slot (32 KiB)

  __shared__ __align__(16) unsigned short lds[4 * SLOT];

  const int t = threadIdx.x;
  const int w = t >> 6;
  const int lane = t & 63;
  const int e = blockIdx.y;

  // bijective XCD swizzle (gridDim.x % 8 == 0: 176 and 128)
  const int cpx = gridDim.x >> 3;
  const int bid = (blockIdx.x & 7) * cpx + (blockIdx.x >> 3);
  const int m0 = (bid / NB_N) << 8;
  const int n0 = (bid % NB_N) * BN;

  const unsigned short* Ae  = A  + (size_t)e * 4096 * KDIM;
  const unsigned short* Be0 = B0 + (size_t)e * NDIM * KDIM;

  // ---- staging sources: 4 panels per wave per sub-tile -------------------
  // panel = 16 rows x 32 k (1 KiB). global_load_lds lane l -> LDS row l>>2,
  // chunk-slot l&3 (linear). Swizzle: slot s of row r holds logical chunk
  // s ^ ((r>>1)&3), so lane l fetches global chunk (l&3) ^ ((l>>3)&3).
  const int prow = lane >> 2;
  const int pcol = (((lane & 3) ^ ((lane >> 3) & 3)) << 3);

  const unsigned short* s0 = Ae + (size_t)(m0 + (w << 4) + prow) * KDIM + pcol;
  const unsigned short* s1 = Ae + (size_t)(m0 + ((w + 8) << 4) + prow) * KDIM + pcol;
  const unsigned short* s2;
  const unsigned short* s3;
  if constexpr (FUSED) {
    const unsigned short* Be1 = B1 + (size_t)e * NDIM * KDIM;
    s2 = Be0 + (size_t)(n0 + (w << 4) + prow) * KDIM + pcol;
    s3 = Be1 + (size_t)(n0 + (w << 4) + prow) * KDIM + pcol;
  } else {
    s2 = Be0 + (size_t)(n0 + (w << 4) + prow) * KDIM + pcol;
    s3 = Be0 + (size_t)(n0 + ((w + 8) << 4) + prow) * KDIM + pcol;
  }
  const int d0 = (w << 9);                                      // A panel w
  const int d1 = ((w + 8) << 9);                                // A panel w+8
  const int d2 = 8192 + (w << 9);                               // B panel w
  const int d3 = FUSED ? (12288 + (w << 9))                     // B1 panel w
                       : (8192 + ((w + 8) << 9));               // B panel w+8

  auto stageA = [&](int slot) {
    unsigned short* b = &lds[slot * SLOT];
    gload16(s0, b + d0); s0 += 32;
    gload16(s1, b + d1); s1 += 32;
  };
  auto stageB = [&](int slot) {
    unsigned short* b = &lds[slot * SLOT];
    gload16(s2, b + d2); s2 += 32;
    gload16(s3, b + d3); s3 += 32;
  };

  // ---- wave -> output sub-tile -------------------------------------------
  const int wm = FUSED ? ((w >> 1) << 6) : ((w >> 2) << 7);
  const int wn = FUSED ? ((w & 1) << 6) : ((w & 3) << 6);
  const int apan = wm >> 4;       // first A panel of this wave
  const int bpan = wn >> 4;       // first B panel of this wave
  const int lm = lane & 15;
  const int kq = lane >> 4;
  // fragment read: row lm, logical chunk kq at stored slot kq^((lm>>1)&3).
  // Lane-constant -> zero loop VALU. 8 consecutive rows cover all 32 banks
  // exactly once (m97-verified conflict-free pattern).
  const int fo = lm * 4 + (kq ^ ((lm >> 1) & 3));  // bf16x8 index in panel

  constexpr int NMI = FUSED ? 4 : 8;
  f32x4 acc0[NMI][4];
  f32x4 acc1[FUSED ? 4 : 1][4];
  const f32x4 z = {0.f, 0.f, 0.f, 0.f};
#pragma unroll
  for (int mi = 0; mi < NMI; ++mi)
#pragma unroll
    for (int nj = 0; nj < 4; ++nj) acc0[mi][nj] = z;
  if constexpr (FUSED) {
#pragma unroll
    for (int mi = 0; mi < 4; ++mi)
#pragma unroll
      for (int nj = 0; nj < 4; ++nj) acc1[mi][nj] = z;
  }

  bf16x8 af[4], bf0[4], bf1[4];

  // ---- prologue: stage sub-tiles 0..2 ------------------------------------
  stageA(0); stageB(0);
  stageA(1); stageB(1);
  stageA(2); stageB(2);
  asm volatile("s_waitcnt vmcnt(8)" ::: "memory");  // sub-tile 0 complete
  __builtin_amdgcn_s_barrier();

  for (int s = 0; s < NS; ++s) {
    const unsigned short* buf = &lds[(s & 3) * SLOT];
    const bf16x8* pA   = (const bf16x8*)buf;
    const bf16x8* pB   = (const bf16x8*)(buf + 8192);
    const bf16x8* pB1v = (const bf16x8*)(buf + 12288);
    const bool pf = (s + 3 < NS);
    const int ps = (s + 3) & 3;

    // -------- phase A --------
#pragma unroll
    for (int mi = 0; mi < 4; ++mi) af[mi] = pA[(apan + mi) * 64 + fo];
#pragma unroll
    for (int nj = 0; nj < 4; ++nj) bf0[nj] = pB[(bpan + nj) * 64 + fo];
    if (pf) stageA(ps);
    __builtin_amdgcn_s_barrier();
    __builtin_amdgcn_s_setprio(1);
#pragma unroll
    for (int mi = 0; mi < 4; ++mi)
#pragma unroll
      for (int nj = 0; nj < 4; ++nj)
        acc0[mi][nj] = __builtin_amdgcn_mfma_f32_16x16x32_bf16(
            af[mi], bf0[nj], acc0[mi][nj], 0, 0, 0);
    __builtin_amdgcn_s_setprio(0);
    __builtin_amdgcn_s_barrier();

    // -------- phase B --------
    if constexpr (FUSED) {
#pragma unroll
      for (int nj = 0; nj < 4; ++nj) bf1[nj] = pB1v[(bpan + nj) * 64 + fo];
    } else {
#pragma unroll
      for (int mi = 0; mi < 4; ++mi) af[mi] = pA[(apan + 4 + mi) * 64 + fo];
    }
    if (pf) stageB(ps);
    __builtin_amdgcn_s_barrier();
    __builtin_amdgcn_s_setprio(1);
    if constexpr (FUSED) {
#pragma unroll
      for (int mi = 0; mi < 4; ++mi)
#pragma unroll
        for (int nj = 0; nj < 4; ++nj)
          acc1[mi][nj] = __builtin_amdgcn_mfma_f32_16x16x32_bf16(
              af[mi], bf1[nj], acc1[mi][nj], 0, 0, 0);
    } else {
#pragma unroll
      for (int mi = 0; mi < 4; ++mi)
#pragma unroll
        for (int nj = 0; nj < 4; ++nj)
          acc0[4 + mi][nj] = __builtin_amdgcn_mfma_f32_16x16x32_bf16(
              af[mi], bf0[nj], acc0[4 + mi][nj], 0, 0, 0);
    }
    __builtin_amdgcn_s_setprio(0);
    // counted wait: sub-tile s+1's loads (issued in step s-2) must be done;
    // leave newer sub-tiles' loads in flight. Exact tail counts.
    if (s + 3 < NS)      asm volatile("s_waitcnt vmcnt(8)" ::: "memory");
    else if (s + 2 < NS) asm volatile("s_waitcnt vmcnt(4)" ::: "memory");
    else if (s + 1 < NS) asm volatile("s_waitcnt vmcnt(0)" ::: "memory");
    __builtin_amdgcn_s_barrier();
  }

  // ---- epilogue: C/D layout col=lane&15, row=(lane>>4)*4+reg -------------
  const size_t cbase = (size_t)e * 4096 * NDIM;
  if constexpr (F32OUT) {
    float* C = (float*)Cout + cbase;
#pragma unroll
    for (int mi = 0; mi < NMI; ++mi)
#pragma unroll
      for (int nj = 0; nj < 4; ++nj)
#pragma unroll
        for (int i = 0; i < 4; ++i) {
          const int row = m0 + wm + (mi << 4) + (kq << 2) + i;
          const int col = n0 + wn + (nj << 4) + lm;
          C[(size_t)row * NDIM + col] = acc0[mi][nj][i];
        }
  } else {
    unsigned short* C = (unsigned short*)Cout + cbase;
#pragma unroll
    for (int mi = 0; mi < 4; ++mi)
#pragma unroll
      for (int nj = 0; nj < 4; ++nj)
#pragma unroll
        for (int i = 0; i < 4; ++i) {
          const int row = m0 + wm + (mi << 4) + (kq << 2) + i;
          const int col = n0 + wn + (nj << 4) + lm;
          const float g = acc0[mi][nj][i];
          const float d = acc1[mi][nj][i];
          C[(size_t)row * NDIM + col] = f2bf(g / (1.0f + __expf(-g)) * d);
        }
  }
}

extern "C" void kernel_launch(void* const* d_in, const int* in_sizes, int n_in,
                              void* d_out, int out_size, void* d_ws, size_t ws_size,
                              hipStream_t stream) {
  const float* x    = (const float*)d_in[0];  // [8][4096][2048] fp32
  const float* gate = (const float*)d_in[1];  // [8][2048][1408] fp32
  const float* down = (const float*)d_in[2];  // [8][2048][1408] fp32
  const float* up   = (const float*)d_in[3];  // [8][1408][2048] fp32

  // d_out doubles as scratch for x_bf16 (134 MB < 268 MB out buffer);
  // GEMM2 overwrites it with the final fp32 result (stream-ordered, and
  // GEMM2 never reads d_out).
  unsigned short* xb = (unsigned short*)d_out;

  char* ws = (char*)d_ws;
  unsigned short* h    = (unsigned short*)ws;                   // 92,274,688 B
  unsigned short* bufG = (unsigned short*)(ws + 92274688ull);   // 46,137,344 B (gate^T, then up^T)
  unsigned short* bufD = (unsigned short*)(ws + 138412032ull);  // 46,137,344 B (down^T)
  // total ws need: 184,549,376 B

  const long nx = 8L * 4096 * 2048;
  cvt_f32_bf16<<<8192, 256, 0, stream>>>(x, xb, nx);

  dim3 tb(32, 8, 1);
  // gate/down: fp32 [2048][1408] -> bf16 [1408][2048]
  trcvt<<<dim3(44, 64, 8), tb, 0, stream>>>(gate, bufG, 2048, 1408);
  trcvt<<<dim3(44, 64, 8), tb, 0, stream>>>(down, bufD, 2048, 1408);

  // h = silu(x@gate) * (x@down):  M=4096, N=1408, K=2048, bf16 out
  // grid: 16 M-blocks x 11 N-blocks = 176 per expert (%8==0)
  gemm_ring<2048, 1408, true, false><<<dim3(176, 8), 512, 0, stream>>>(xb, bufG, bufD, h);

  // up: fp32 [1408][2048] -> bf16 [2048][1408]  (reuses bufG)
  trcvt<<<dim3(64, 44, 8), tb, 0, stream>>>(up, bufG, 1408, 2048);

  // out = h @ up:  M=4096, N=2048, K=1408, fp32 out
  // grid: 16 M-blocks x 8 N-blocks = 128 per expert (%8==0)
  gemm_ring<1408, 2048, false, true><<<dim3(128, 8), 512, 0, stream>>>(h, bufG, nullptr, (float*)d_out);
}

// Round 4
// 1167.475 us; speedup vs baseline: 1.2499x; 1.0144x over previous
//
#include <hip/hip_runtime.h>
#include <hip/hip_bf16.h>

// GroupedExperts: out = (silu(x@gate) * (x@down)) @ up  per expert.
// E=8, T=4096, D_IN=2048, D_H=1408. fp32 in/out, bf16 MFMA internally.
//
// Round-4 GEMM: ring-4 LDS (128 KiB), BK=32 sub-tiles, 3-ahead staging,
// counted vmcnt, and now ONE barrier per K-step with ds_reads software-
// pipelined across the MFMA clusters so the LDS pipe runs UNDER the matrix
// pipe (round-3 counters showed them alternating: 1240cy MFMA + 1150cy LDS
// = 2870cy/step measured; overlap floor is ~1450).

typedef __bf16 bf16x8 __attribute__((ext_vector_type(8)));
typedef float  f32x4  __attribute__((ext_vector_type(4)));

__device__ __forceinline__ void gload16(const void* g, void* l) {
  // async global->LDS, 16B per lane; LDS dest = wave-uniform base + lane*16
  __builtin_amdgcn_global_load_lds((const __attribute__((address_space(1))) void*)g,
                                   (__attribute__((address_space(3))) void*)l,
                                   16, 0, 0);
}

__device__ __forceinline__ unsigned short f2bf(float f) {
  union { float fv; unsigned u; } v; v.fv = f;
  unsigned r = (v.u + 0x7fffu + ((v.u >> 16) & 1u)) >> 16;  // RNE
  return (unsigned short)r;
}

// ------------- cast fp32 -> bf16, flat, vectorized -------------------------
__global__ __launch_bounds__(256)
void cvt_f32_bf16(const float* __restrict__ in, unsigned short* __restrict__ out,
                  long n) {
  long i = ((long)blockIdx.x * 256 + threadIdx.x) * 4;
  const long stride = (long)gridDim.x * 1024;
  for (; i < n; i += stride) {
    const float4 v = *(const float4*)(in + i);
    ushort4 o;
    o.x = f2bf(v.x); o.y = f2bf(v.y); o.z = f2bf(v.z); o.w = f2bf(v.w);
    *(ushort4*)(out + i) = o;
  }
}

// ------------- transpose+cast: fp32 [E][R][C] -> bf16 [E][C][R] ------------
// 64x64 tiles, 512 threads: 256B coalesced loads, 128B coalesced stores
// (round-3 version stored 64B/wave segments). tile[64][65]: 2-way LDS
// aliasing only (free, m136).
__global__ __launch_bounds__(512)
void trcvt(const float* __restrict__ in, unsigned short* __restrict__ out,
           int R, int C) {
  __shared__ unsigned short tile[64][65];
  const float* src = in + (size_t)blockIdx.z * R * C;
  unsigned short* dst = out + (size_t)blockIdx.z * R * C;
  const int c0 = blockIdx.x << 6, r0 = blockIdx.y << 6;
  const int tx = threadIdx.x, ty = threadIdx.y;  // block (64,8)
#pragma unroll
  for (int i = 0; i < 64; i += 8)
    tile[ty + i][tx] = f2bf(src[(size_t)(r0 + ty + i) * C + (c0 + tx)]);
  __syncthreads();
#pragma unroll
  for (int i = 0; i < 64; i += 8)
    dst[(size_t)(c0 + ty + i) * R + (r0 + tx)] = tile[tx][ty + i];
}

// --------------- ring-pipelined GEMM: C[4096][NDIM] = A[4096][KDIM] @ B^T --
// FUSED: C = silu(A@B0)*(A@B1), bf16 out, BM=256 BN=128 (two B mats).
// else:  C = A@B0, fp32 out,            BM=256 BN=256.
// 512 threads = 8 waves, 1 block/CU (128 KiB LDS).
//
// Per K-step s (one barrier):
//   g1 reads (4 b128: frags for MFMA-B of step s)      <- overlap MFMA-A
//   MFMA-A (16)
//   vmcnt(4) [subtile s+1 landed] ; s_barrier [slot s-1 reads all retired]
//   gloads subtile s+3 -> slot (s-1)&3
//   g2 reads (8 b128: A+B frags for MFMA-A of step s+1) <- overlap MFMA-B
//   MFMA-B (16)
// Fragment regs double-buffered with static names (2-step unrolled loop).
template <int KDIM, int NDIM, bool FUSED, bool F32OUT>
__global__ __launch_bounds__(512, 2)
void gemm_ring(const unsigned short* __restrict__ A,
               const unsigned short* __restrict__ B0,
               const unsigned short* __restrict__ B1,
               void* __restrict__ Cout) {
  constexpr int BN   = FUSED ? 128 : 256;
  constexpr int NB_N = NDIM / BN;
  constexpr int NS   = KDIM / 32;     // K-steps (64 / 44 — both even)
  constexpr int SLOT = 16384;         // ushorts per ring slot (32 KiB)

  __shared__ __align__(16) unsigned short lds[4 * SLOT];

  const int t = threadIdx.x;
  const int w = t >> 6;
  const int lane = t & 63;
  const int e = blockIdx.y;

  // bijective XCD swizzle (gridDim.x % 8 == 0: 176 and 128)
  const int cpx = gridDim.x >> 3;
  const int bid = (blockIdx.x & 7) * cpx + (blockIdx.x >> 3);
  const int m0 = (bid / NB_N) << 8;
  const int n0 = (bid % NB_N) * BN;

  const unsigned short* Ae  = A  + (size_t)e * 4096 * KDIM;
  const unsigned short* Be0 = B0 + (size_t)e * NDIM * KDIM;

  // staging: panel = 16 rows x 32 k (1 KiB). Lane l -> LDS row l>>2, slot
  // l&3 (linear dest). Swizzle: slot c of row r holds logical chunk
  // c ^ ((r>>1)&3) -> lane fetches global chunk (l&3)^((l>>3)&3).
  const int prow = lane >> 2;
  const int pcol = (((lane & 3) ^ ((lane >> 3) & 3)) << 3);

  const unsigned short* s0 = Ae + (size_t)(m0 + (w << 4) + prow) * KDIM + pcol;
  const unsigned short* s1 = Ae + (size_t)(m0 + ((w + 8) << 4) + prow) * KDIM + pcol;
  const unsigned short* s2;
  const unsigned short* s3;
  if constexpr (FUSED) {
    const unsigned short* Be1 = B1 + (size_t)e * NDIM * KDIM;
    s2 = Be0 + (size_t)(n0 + (w << 4) + prow) * KDIM + pcol;
    s3 = Be1 + (size_t)(n0 + (w << 4) + prow) * KDIM + pcol;
  } else {
    s2 = Be0 + (size_t)(n0 + (w << 4) + prow) * KDIM + pcol;
    s3 = Be0 + (size_t)(n0 + ((w + 8) << 4) + prow) * KDIM + pcol;
  }
  const int d0 = (w << 9);
  const int d1 = ((w + 8) << 9);
  const int d2 = 8192 + (w << 9);
  const int d3 = FUSED ? (12288 + (w << 9)) : (8192 + ((w + 8) << 9));

  auto stage = [&](int slot) {
    unsigned short* b = &lds[slot * SLOT];
    gload16(s0, b + d0); s0 += 32;
    gload16(s1, b + d1); s1 += 32;
    gload16(s2, b + d2); s2 += 32;
    gload16(s3, b + d3); s3 += 32;
  };

  // wave -> output sub-tile
  const int wm = FUSED ? ((w >> 1) << 6) : ((w >> 2) << 7);
  const int wn = FUSED ? ((w & 1) << 6) : ((w & 3) << 6);
  const int apan = wm >> 4;
  const int bpan = wn >> 4;
  const int lm = lane & 15;
  const int kq = lane >> 4;
  // frag read: row lm, logical chunk kq at stored slot kq^((lm>>1)&3);
  // lane-constant; 8 consecutive rows cover all 32 banks (conflict-free,
  // round-3 measured SQ_LDS_BANK_CONFLICT = 0).
  const int fo = lm * 4 + (kq ^ ((lm >> 1) & 3));

  constexpr int NMI = FUSED ? 4 : 8;
  f32x4 acc0[NMI][4];
  f32x4 acc1[FUSED ? 4 : 1][4];
  const f32x4 z = {0.f, 0.f, 0.f, 0.f};
#pragma unroll
  for (int mi = 0; mi < NMI; ++mi)
#pragma unroll
    for (int nj = 0; nj < 4; ++nj) acc0[mi][nj] = z;
  if constexpr (FUSED) {
#pragma unroll
    for (int mi = 0; mi < 4; ++mi)
#pragma unroll
      for (int nj = 0; nj < 4; ++nj) acc1[mi][nj] = z;
  }

  // fragment register sets (static names; no runtime indexing -> no scratch)
  bf16x8 afX[4], afY[4];          // A-lo double buffer
  bf16x8 bfX[4], bfY[4];          // B0 double buffer (non-FUSED); FUSED uses bfX only
  bf16x8 g1[4];                   // per-step: FUSED = B1 frags; else A-hi frags

  // ---- prologue: stage sub-tiles 0..2; read step-0 A-frags ---------------
  stage(0); stage(1); stage(2);
  asm volatile("s_waitcnt vmcnt(8)" ::: "memory");  // sub-tile 0 landed
  __builtin_amdgcn_s_barrier();
  {
    const bf16x8* pA = (const bf16x8*)&lds[0];
    const bf16x8* pB = (const bf16x8*)&lds[8192];
#pragma unroll
    for (int mi = 0; mi < 4; ++mi) afX[mi] = pA[(apan + mi) * 64 + fo];
#pragma unroll
    for (int nj = 0; nj < 4; ++nj) bfX[nj] = pB[(bpan + nj) * 64 + fo];
  }

  // STEP(s, afc, afn, bfc, bfn): afc/bfc = current frags, afn/bfn = next.
#define STEP(S, AFC, AFN, BFC, BFN)                                            \
  {                                                                            \
    const int s_ = (S);                                                        \
    const unsigned short* buf = &lds[(s_ & 3) * SLOT];                         \
    /* g1: frags for MFMA-B of this step (overlaps MFMA-A) */                  \
    if constexpr (FUSED) {                                                     \
      const bf16x8* pB1 = (const bf16x8*)(buf + 12288);                        \
      _Pragma("unroll") for (int nj = 0; nj < 4; ++nj)                         \
        g1[nj] = pB1[(bpan + nj) * 64 + fo];                                   \
    } else {                                                                   \
      const bf16x8* pA = (const bf16x8*)buf;                                   \
      _Pragma("unroll") for (int mi = 0; mi < 4; ++mi)                         \
        g1[mi] = pA[(apan + 4 + mi) * 64 + fo];                                \
    }                                                                          \
    __builtin_amdgcn_s_setprio(1);                                             \
    _Pragma("unroll") for (int mi = 0; mi < 4; ++mi)                           \
      _Pragma("unroll") for (int nj = 0; nj < 4; ++nj)                         \
        acc0[mi][nj] = __builtin_amdgcn_mfma_f32_16x16x32_bf16(                \
            AFC[mi], BFC[nj], acc0[mi][nj], 0, 0, 0);                          \
    __builtin_amdgcn_s_setprio(0);                                             \
    /* counted wait for sub-tile s+1; barrier also closes slot s-1 reads */    \
    if (s_ < NS - 2)      asm volatile("s_waitcnt vmcnt(4)" ::: "memory");     \
    else if (s_ < NS - 1) asm volatile("s_waitcnt vmcnt(0)" ::: "memory");     \
    if (s_ < NS - 1) __builtin_amdgcn_s_barrier();                             \
    if (s_ + 3 < NS) stage((s_ + 3) & 3);                                      \
    /* g2: next step's A-phase frags (overlaps MFMA-B) */                      \
    if (s_ < NS - 1) {                                                         \
      const unsigned short* nbuf = &lds[((s_ + 1) & 3) * SLOT];                \
      const bf16x8* pAn = (const bf16x8*)nbuf;                                 \
      const bf16x8* pBn = (const bf16x8*)(nbuf + 8192);                        \
      _Pragma("unroll") for (int mi = 0; mi < 4; ++mi)                         \
        AFN[mi] = pAn[(apan + mi) * 64 + fo];                                  \
      _Pragma("unroll") for (int nj = 0; nj < 4; ++nj)                         \
        BFN[nj] = pBn[(bpan + nj) * 64 + fo];                                  \
    }                                                                          \
    __builtin_amdgcn_s_setprio(1);                                             \
    if constexpr (FUSED) {                                                     \
      _Pragma("unroll") for (int mi = 0; mi < 4; ++mi)                         \
        _Pragma("unroll") for (int nj = 0; nj < 4; ++nj)                       \
          acc1[mi][nj] = __builtin_amdgcn_mfma_f32_16x16x32_bf16(              \
              AFC[mi], g1[nj], acc1[mi][nj], 0, 0, 0);                         \
    } else {                                                                   \
      _Pragma("unroll") for (int mi = 0; mi < 4; ++mi)                         \
        _Pragma("unroll") for (int nj = 0; nj < 4; ++nj)                       \
          acc0[4 + mi][nj] = __builtin_amdgcn_mfma_f32_16x16x32_bf16(          \
              g1[mi], BFC[nj], acc0[4 + mi][nj], 0, 0, 0);                     \
    }                                                                          \
    __builtin_amdgcn_s_setprio(0);                                             \
  }

  // NS is even for both instantiations (64, 44)
  for (int s = 0; s < NS; s += 2) {
    STEP(s,     afX, afY, bfX, bfY)
    STEP(s + 1, afY, afX, bfY, bfX)
  }
#undef STEP
  // FUSED note: MFMA-B reads AFC (A frags) and g1 (B1); bfX/bfY next-buffer
  // writes only land in regs MFMA-A already consumed -> compiler-visible WAR.

  // ---- epilogue: C/D layout col=lane&15, row=(lane>>4)*4+reg -------------
  const size_t cbase = (size_t)e * 4096 * NDIM;
  if constexpr (F32OUT) {
    float* C = (float*)Cout + cbase;
#pragma unroll
    for (int mi = 0; mi < NMI; ++mi)
#pragma unroll
      for (int nj = 0; nj < 4; ++nj)
#pragma unroll
        for (int i = 0; i < 4; ++i) {
          const int row = m0 + wm + (mi << 4) + (kq << 2) + i;
          const int col = n0 + wn + (nj << 4) + lm;
          C[(size_t)row * NDIM + col] = acc0[mi][nj][i];
        }
  } else {
    unsigned short* C = (unsigned short*)Cout + cbase;
#pragma unroll
    for (int mi = 0; mi < 4; ++mi)
#pragma unroll
      for (int nj = 0; nj < 4; ++nj)
#pragma unroll
        for (int i = 0; i < 4; ++i) {
          const int row = m0 + wm + (mi << 4) + (kq << 2) + i;
          const int col = n0 + wn + (nj << 4) + lm;
          const float g = acc0[mi][nj][i];
          const float d = acc1[mi][nj][i];
          C[(size_t)row * NDIM + col] = f2bf(g / (1.0f + __expf(-g)) * d);
        }
  }
}

extern "C" void kernel_launch(void* const* d_in, const int* in_sizes, int n_in,
                              void* d_out, int out_size, void* d_ws, size_t ws_size,
                              hipStream_t stream) {
  const float* x    = (const float*)d_in[0];  // [8][4096][2048] fp32
  const float* gate = (const float*)d_in[1];  // [8][2048][1408] fp32
  const float* down = (const float*)d_in[2];  // [8][2048][1408] fp32
  const float* up   = (const float*)d_in[3];  // [8][1408][2048] fp32

  // d_out doubles as scratch for x_bf16 (134 MB < 268 MB out buffer);
  // GEMM2 overwrites it with the final fp32 result (stream-ordered, and
  // GEMM2 never reads d_out).
  unsigned short* xb = (unsigned short*)d_out;

  char* ws = (char*)d_ws;
  unsigned short* h    = (unsigned short*)ws;                   // 92,274,688 B
  unsigned short* bufG = (unsigned short*)(ws + 92274688ull);   // 46,137,344 B (gate^T, then up^T)
  unsigned short* bufD = (unsigned short*)(ws + 138412032ull);  // 46,137,344 B (down^T)
  // total ws need: 184,549,376 B

  const long nx = 8L * 4096 * 2048;
  cvt_f32_bf16<<<8192, 256, 0, stream>>>(x, xb, nx);

  dim3 tb(64, 8, 1);
  // gate/down: fp32 [2048][1408] -> bf16 [1408][2048]
  trcvt<<<dim3(22, 32, 8), tb, 0, stream>>>(gate, bufG, 2048, 1408);
  trcvt<<<dim3(22, 32, 8), tb, 0, stream>>>(down, bufD, 2048, 1408);

  // h = silu(x@gate) * (x@down):  M=4096, N=1408, K=2048, bf16 out
  gemm_ring<2048, 1408, true, false><<<dim3(176, 8), 512, 0, stream>>>(xb, bufG, bufD, h);

  // up: fp32 [1408][2048] -> bf16 [2048][1408]  (reuses bufG)
  trcvt<<<dim3(32, 22, 8), tb, 0, stream>>>(up, bufG, 1408, 2048);

  // out = h @ up:  M=4096, N=2048, K=1408, fp32 out
  gemm_ring<1408, 2048, false, true><<<dim3(128, 8), 512, 0, stream>>>(h, bufG, nullptr, (float*)d_out);
}